// Round 4
// baseline (1700.336 us; speedup 1.0000x reference)
//
#include <hip/hip_runtime.h>
#include <hip/hip_bf16.h>
#include <cstdint>

#define TSTEPS 512
#define BATCH  256
#define HID    512
#define INP    64
#define NGRP   16          // batch groups
#define GROWS  16          // batch rows per group
#define NSL    16          // WG slices per group (32 hid cols each)
#define NWG    256
#define KTH    16          // h K-tiles (512/32)

typedef __attribute__((ext_vector_type(8))) short short8;
typedef __attribute__((ext_vector_type(4))) float f32x4;
typedef __attribute__((ext_vector_type(2))) unsigned long long ull2;

// workspace layout
#define HB0_OFF   0
#define HB1_OFF   (BATCH*HID*2)
#define HT_OFF    (2*BATCH*HID*2)
#define FLAGS_OFF (HT_OFF + BATCH*HID*4)          // 16 grp x 4 slot x 16 sl x 64B
#define FLAGS_SZ  (NGRP*4*NSL*64)
#define CNT_OFF   (FLAGS_OFF + FLAGS_SZ)
#define ZERO2_SZ  (FLAGS_SZ + 64)

__device__ __forceinline__ unsigned short f2bf(float f) {
    unsigned u = __float_as_uint(f);
    return (unsigned short)((u + 0x7FFFu + ((u >> 16) & 1u)) >> 16);  // RNE
}
__device__ __forceinline__ short8 pack8(float4 a0, float4 a1) {
    short8 v;
    v[0]=(short)f2bf(a0.x); v[1]=(short)f2bf(a0.y); v[2]=(short)f2bf(a0.z); v[3]=(short)f2bf(a0.w);
    v[4]=(short)f2bf(a1.x); v[5]=(short)f2bf(a1.y); v[6]=(short)f2bf(a1.z); v[7]=(short)f2bf(a1.w);
    return v;
}
__device__ __forceinline__ float sigm(float x)  { return 1.0f/(1.0f + __expf(-x)); }
__device__ __forceinline__ float tanhf_(float x){ return 2.0f/(1.0f + __expf(-2.0f*x)) - 1.0f; }

__global__ void __launch_bounds__(256, 1)
lstm_persist(const float* __restrict__ x,   const float* __restrict__ Wih,
             const float* __restrict__ Whh, const float* __restrict__ bih,
             const float* __restrict__ bhh, const float* __restrict__ Whead,
             const float* __restrict__ bhead, float* __restrict__ out,
             char* __restrict__ ws)
{
    extern __shared__ char lds[];   // 128 KiB requested (forces 1 WG/CU); ~16 KiB used
    const int tid  = threadIdx.x;
    const int lane = tid & 63;
    const int wv   = tid >> 6;
    const int l15  = lane & 15, lq = lane >> 4, l7 = lane & 7;

    unsigned short* hb0 = (unsigned short*)(ws + HB0_OFF);
    unsigned short* hb1 = (unsigned short*)(ws + HB1_OFF);
    float* hT  = (float*)(ws + HT_OFF);
    unsigned* flags = (unsigned*)(ws + FLAGS_OFF);
    int* cnt   = (int*)(ws + CNT_OFF);

    // ---- self-organize by XCD: 32 WGs/XCD (capacity-guaranteed) -> 2 groups x 16 slices ----
    int* org = (int*)(lds + 131056);   // tail of dynamic LDS, untouched elsewhere
    if (tid == 0) {
        unsigned xcd;
        asm volatile("s_getreg_b32 %0, hwreg(HW_REG_XCC_ID)" : "=s"(xcd));
        xcd &= 7u;
        int slot = __hip_atomic_fetch_add(&cnt[xcd], 1, __ATOMIC_RELAXED, __HIP_MEMORY_SCOPE_AGENT) & 31;
        org[0] = (int)xcd * 2 + (slot >> 4);
        org[1] = slot & 15;
    }
    __syncthreads();
    const int g  = org[0];
    const int sl = org[1];
    const int hbase = sl*32 + wv*8;        // wave's hidden-col base
    const int gsel  = l15 >> 3;            // gate select within N-tile

    // ---- W_hh fragments resident in VGPRs: 16 Ktiles x 2 Ntiles x 4 VGPR = 128 ----
    // Ntile0 cols = [gate i: hid 0..7 | gate f: hid 0..7]; Ntile1 = [g | o]
    short8 whh[KTH][2];
    #pragma unroll
    for (int kt = 0; kt < KTH; ++kt)
        #pragma unroll
        for (int nt = 0; nt < 2; ++nt) {
            int grow = (nt*2 + gsel)*HID + hbase + l7;
            const float4* p = (const float4*)(Whh + (size_t)grow*HID + kt*32 + lq*8);
            whh[kt][nt] = pack8(p[0], p[1]);
        }
    short8 wihf[2][2];
    #pragma unroll
    for (int kt = 0; kt < 2; ++kt)
        #pragma unroll
        for (int nt = 0; nt < 2; ++nt) {
            int grow = (nt*2 + gsel)*HID + hbase + l7;
            const float4* p = (const float4*)(Wih + (size_t)grow*INP + kt*32 + lq*8);
            wihf[kt][nt] = pack8(p[0], p[1]);
        }
    float bias0, bias1;
    { int gr = (0*2 + gsel)*HID + hbase + l7; bias0 = bih[gr] + bhh[gr]; }
    { int gr = (1*2 + gsel)*HID + hbase + l7; bias1 = bih[gr] + bhh[gr]; }

    unsigned short* hg0 = hb0 + (size_t)g*GROWS*HID;
    unsigned short* hg1 = hb1 + (size_t)g*GROWS*HID;
    float*          hTg = hT  + (size_t)g*GROWS*HID;

    // staging map: thread -> (cluster skt = tid>>4 stages producer skt's slice)
    const int skt = tid >> 4, sr = tid & 15;
    char* swp = lds + skt*1024 + sr*16;            // + s*256 for k-sub-block s=0..3
    const char* srp = lds + lane*16;               // frag read: + kt*1024  (conflict-free)

    // per-producer flag addresses (64B padded): [g][slot][sl]
    unsigned* flag_w = flags + ((g*4 + 0)*NSL + sl)*16;     // + slot*NSL*16
    unsigned* flag_r = flags + ((g*4 + 0)*NSL + skt)*16;    // + slot*NSL*16

    const float* xrow = x + ((size_t)(g*GROWS + l15)*TSTEPS)*INP + lq*8;

    f32x4 cst = {0.f, 0.f, 0.f, 0.f};

    // x prefetch for t=0
    float4 xv0 = *(const float4*)(xrow);
    float4 xv1 = *(const float4*)(xrow + 4);
    float4 xv2 = *(const float4*)(xrow + 32);
    float4 xv3 = *(const float4*)(xrow + 36);

    #pragma clang loop unroll(disable)
    for (int t = 0; t < TSTEPS; ++t) {
        f32x4 acc0 = {bias0, bias0, bias0, bias0};
        f32x4 acc1 = {bias1, bias1, bias1, bias1};

        // x-projection (independent of h_{t-1}) from prefetched regs
        {
            short8 af0 = pack8(xv0, xv1);
            short8 af1 = pack8(xv2, xv3);
            acc0 = __builtin_amdgcn_mfma_f32_16x16x32_bf16(af0, wihf[0][0], acc0, 0, 0, 0);
            acc1 = __builtin_amdgcn_mfma_f32_16x16x32_bf16(af0, wihf[0][1], acc1, 0, 0, 0);
            acc0 = __builtin_amdgcn_mfma_f32_16x16x32_bf16(af1, wihf[1][0], acc0, 0, 0, 0);
            acc1 = __builtin_amdgcn_mfma_f32_16x16x32_bf16(af1, wihf[1][1], acc1, 0, 0, 0);
        }
        // x loads for t+1: issue BEFORE the spin so HBM latency hides under the wait
        if (t + 1 < TSTEPS) {
            const float* xn = xrow + (size_t)(t+1)*INP;
            xv0 = *(const float4*)(xn);
            xv1 = *(const float4*)(xn + 4);
            xv2 = *(const float4*)(xn + 32);
            xv3 = *(const float4*)(xn + 36);
        }
        __builtin_amdgcn_sched_barrier(0);

        // fine-grained: each 16-thread cluster waits only for ITS producer, then stages
        if (t) {
            const unsigned* fl = flag_r + (((t-1)&3)*NSL)*16;
            while (__hip_atomic_load(fl, __ATOMIC_RELAXED, __HIP_MEMORY_SCOPE_AGENT) < (unsigned)t) {}
            asm volatile("" ::: "memory");
        }
        {
            const unsigned long long* gq = (const unsigned long long*)
                ((const char*)((t & 1) ? hg1 : hg0) + sr*1024 + skt*64);
            unsigned long long hv[8];
            #pragma unroll
            for (int j = 0; j < 8; ++j)
                hv[j] = __hip_atomic_load(gq + j, __ATOMIC_RELAXED, __HIP_MEMORY_SCOPE_AGENT);
            #pragma unroll
            for (int s = 0; s < 4; ++s) {
                ull2 w; w[0] = hv[2*s]; w[1] = hv[2*s+1];
                *(ull2*)(swp + s*256) = w;
            }
        }
        __syncthreads();

        #pragma unroll
        for (int kt = 0; kt < KTH; ++kt) {
            short8 a = *(const short8*)(srp + kt*1024);
            acc0 = __builtin_amdgcn_mfma_f32_16x16x32_bf16(a, whh[kt][0], acc0, 0, 0, 0);
            acc1 = __builtin_amdgcn_mfma_f32_16x16x32_bf16(a, whh[kt][1], acc1, 0, 0, 0);
        }

        // epilogue: C layout col=lane&15, row=(lane>>4)*4+r
        unsigned short* hbw = (t & 1) ? hg0 : hg1;
        #pragma unroll
        for (int r = 0; r < 4; ++r) {
            float a0 = acc0[r], a1 = acc1[r];
            float s0 = __shfl_xor(a0, 8);
            float s1 = __shfl_xor(a1, 8);
            bool lo = (l15 < 8);
            float iv = lo ? a0 : s0;
            float fv = lo ? s0 : a0;
            float gv = lo ? a1 : s1;
            float ov = lo ? s1 : a1;
            float c  = sigm(fv)*cst[r] + sigm(iv)*tanhf_(gv);
            cst[r] = c;
            float h  = sigm(ov)*tanhf_(c);
            if (lo) {
                int idx = (lq*4 + r)*HID + hbase + l7;
                hbw[idx] = f2bf(h);
                if (t == TSTEPS-1) hTg[idx] = h;
            }
        }
        __syncthreads();   // drains each wave's vmcnt -> all h stores visible in this XCD's L2
        if (tid == 0)
            __hip_atomic_store(flag_w + ((t&3)*NSL)*16, (unsigned)(t+1),
                               __ATOMIC_RELAXED, __HIP_MEMORY_SCOPE_AGENT);
    }

    // ---- heads: slice-0 WG of each group ----
    if (sl == 0) {
        if (tid < NSL) {
            const unsigned* fl = flags + ((g*4 + ((TSTEPS-1)&3))*NSL + tid)*16;
            while (__hip_atomic_load(fl, __ATOMIC_RELAXED, __HIP_MEMORY_SCOPE_AGENT) < (unsigned)TSTEPS) {}
        }
        asm volatile("" ::: "memory");
        __syncthreads();
        // stage hT tile (16x512 f32 = 32 KiB) into LDS; hT addresses were never read
        // before by this WG (no stale-L1 path) -> plain loads are safe.
        {
            const float4* gp = (const float4*)((const char*)hTg + tid*128);
            float4* wp = (float4*)(lds + tid*128);
            #pragma unroll
            for (int j = 0; j < 8; ++j) wp[j] = gp[j];
        }
        __syncthreads();
        const float* hsm = (const float*)lds;
        for (int idx = tid; idx < 6*GROWS*3; idx += 256) {
            int k = idx / (GROWS*3), rem = idx % (GROWS*3);
            int row = rem / 3, o = rem % 3;
            const float* wp = Whead + ((size_t)k*3 + o)*HID;
            const float* hp = hsm + row*HID;
            float s = 0.f;
            for (int hh = 0; hh < HID; hh += 4) {
                float4 hv = *(const float4*)(hp + hh);
                float4 wv = *(const float4*)(wp + hh);
                s += hv.x*wv.x + hv.y*wv.y + hv.z*wv.z + hv.w*wv.w;
            }
            out[((size_t)k*BATCH + g*GROWS + row)*3 + o] = s + bhead[k*3 + o];
        }
    }
}

extern "C" void kernel_launch(void* const* d_in, const int* in_sizes, int n_in,
                              void* d_out, int out_size, void* d_ws, size_t ws_size,
                              hipStream_t stream) {
    (void)in_sizes; (void)n_in; (void)out_size; (void)ws_size;
    const float* x     = (const float*)d_in[0];
    const float* Wih   = (const float*)d_in[1];
    const float* Whh   = (const float*)d_in[2];
    const float* bih   = (const float*)d_in[3];
    const float* bhh   = (const float*)d_in[4];
    const float* Whead = (const float*)d_in[5];
    const float* bhead = (const float*)d_in[6];
    char* ws = (char*)d_ws;

    (void)hipFuncSetAttribute((const void*)lstm_persist,
                              hipFuncAttributeMaxDynamicSharedMemorySize, 131072);

    // per-launch reset: h_0 = 0, flags = 0, xcd slot counters = 0
    (void)hipMemsetAsync(ws + HB0_OFF, 0, BATCH*HID*2, stream);
    (void)hipMemsetAsync(ws + FLAGS_OFF, 0, ZERO2_SZ, stream);

    hipLaunchKernelGGL(lstm_persist, dim3(NWG), dim3(256), 131072, stream,
                       x, Wih, Whh, bih, bhh, Whead, bhead, (float*)d_out, ws);
}